// Round 12
// baseline (722.426 us; speedup 1.0000x reference)
//
#include <hip/hip_runtime.h>
#include <hip/hip_bf16.h>

#define NB 4096
#define NS 32
#define NI 16
#define NH 32

typedef float f32x2 __attribute__((ext_vector_type(2)));

// Wave-local LDS write->read turnaround: drain lgkm, fence the compiler.
__device__ __forceinline__ void fence() {
    __builtin_amdgcn_wave_barrier();
    asm volatile("s_waitcnt lgkmcnt(0)" ::: "memory");
    __builtin_amdgcn_wave_barrier();
}

// Equal-input permlane swap sums: x[lane] + x[lane^32] / x[lane^16] in all
// lanes, convention-independent (proven R3..R11).
__device__ __forceinline__ float xh32(float x) {
    auto p = __builtin_amdgcn_permlane32_swap(
        (int)__float_as_uint(x), (int)__float_as_uint(x), false, false);
    return __uint_as_float((unsigned)p[0]) + __uint_as_float((unsigned)p[1]);
}
__device__ __forceinline__ float xh16(float x) {
    auto p = __builtin_amdgcn_permlane16_swap(
        (int)__float_as_uint(x), (int)__float_as_uint(x), false, false);
    return __uint_as_float((unsigned)p[0]) + __uint_as_float((unsigned)p[1]);
}

__device__ __forceinline__ f32x2 pkfma(f32x2 a, f32x2 b, f32x2 c) {
    return __builtin_elementwise_fma(a, b, c);   // v_pk_fma_f32
}
__device__ __forceinline__ f32x2 pfm(float a, f32x2 b, f32x2 c) {
    return __builtin_elementwise_fma(f32x2{a, a}, b, c);
}

// R11 diagnosis: LDS read pipe is the bottleneck (40 ds_read_b128 per
// ode_f2 x 8 waves/CU ~ 4448 cyc/round on ONE per-CU pipe). R12: deeper
// k-splits with pk output-pairs halve reads to 20 (weights/lane invariant
// at 80 floats). Reductions via equal-input permlane sums (VALU pipe).
__global__ void __launch_bounds__(256)
__attribute__((amdgpu_waves_per_eu(2, 2)))
odernn_kernel(
    const float* __restrict__ x,    // (B,S,I)
    const float* __restrict__ t,    // (B,S)
    const float* __restrict__ gWih, // (96,16)
    const float* __restrict__ gWhh, // (96,32)
    const float* __restrict__ gbih, // (96)
    const float* __restrict__ gbhh, // (96)
    const float* __restrict__ oW1,  // (64,32)
    const float* __restrict__ ob1,  // (64)
    const float* __restrict__ oW2,  // (32,64)
    const float* __restrict__ ob2,  // (32)
    const float* __restrict__ oW3,  // (32,32)
    const float* __restrict__ ob3,  // (32)
    const float* __restrict__ fW1,  // (64,32)
    const float* __restrict__ fb1,  // (64)
    const float* __restrict__ fW2,  // (1,64)
    const float* __restrict__ fb2,  // (1)
    float* __restrict__ outp)       // (B,1)
{
    const int tid  = threadIdx.x;
    const int lane = tid & 63;
    const int wid  = tid >> 6;
    const int b0   = blockIdx.x * 8 + wid * 2;
    const int b1   = b0 + 1;
    const int r    = lane & 31;     // half-row index (X layout)
    const int hf   = lane >> 5;     // half 0/1
    const int p    = lane & 15;     // quarter-row index (P layout)
    const int q    = lane >> 4;     // quarter 0..3

    // ---- LDS: GRU weights (col-major [col][32 rows]) + per-elem buffers ----
    __shared__ float sWr[48 * 32];
    __shared__ float sWz[48 * 32];
    __shared__ float sWnh[32 * 32];
    __shared__ float sWni[16 * 32];
    __shared__ __align__(16) float buf[4][2][64];

    for (int i = tid; i < 48 * 32; i += 256) {
        int c = i >> 5, r0 = i & 31;
        sWr[i] = (c < 16) ? gWih[r0 * 16 + c]        : gWhh[r0 * 32 + (c - 16)];
        sWz[i] = (c < 16) ? gWih[(32 + r0) * 16 + c] : gWhh[(32 + r0) * 32 + (c - 16)];
    }
    for (int i = tid; i < 32 * 32; i += 256) {
        int c = i >> 5, r0 = i & 31;
        sWnh[i] = gWhh[(64 + r0) * 32 + c];
    }
    for (int i = tid; i < 16 * 32; i += 256) {
        int c = i >> 5, r0 = i & 31;
        sWni[i] = gWih[(64 + r0) * 16 + c];
    }
    __syncthreads();

    float* bufw0 = buf[wid][0];
    float* bufw1 = buf[wid][1];
    const float4* bb0 = reinterpret_cast<const float4*>(bufw0);
    const float4* bb1 = reinterpret_cast<const float4*>(bufw1);

    // ---- ODE weights, pk over OUTPUT pairs; named vars (no alloca) ----
    // S1: outputs {r, r+32}, k in [16hf, 16hf+16)
    f32x2 w1_0, w1_1, w1_2, w1_3, w1_4, w1_5, w1_6, w1_7,
          w1_8, w1_9, w1_10, w1_11, w1_12, w1_13, w1_14, w1_15;
    {
        const float4* A = reinterpret_cast<const float4*>(oW1 + r * 32 + hf * 16);
        const float4* B = reinterpret_cast<const float4*>(oW1 + (r + 32) * 32 + hf * 16);
        float4 a, bq;
#define LW(kk, d0, d1, d2, d3) { a = A[kk]; bq = B[kk]; \
        d0 = f32x2{a.x, bq.x}; d1 = f32x2{a.y, bq.y}; \
        d2 = f32x2{a.z, bq.z}; d3 = f32x2{a.w, bq.w}; }
        LW(0, w1_0, w1_1, w1_2,  w1_3)
        LW(1, w1_4, w1_5, w1_6,  w1_7)
        LW(2, w1_8, w1_9, w1_10, w1_11)
        LW(3, w1_12, w1_13, w1_14, w1_15)
#undef LW
    }
    // S2: outputs {p, p+16}, k in [16q, 16q+16)
    f32x2 w2_0, w2_1, w2_2, w2_3, w2_4, w2_5, w2_6, w2_7,
          w2_8, w2_9, w2_10, w2_11, w2_12, w2_13, w2_14, w2_15;
    {
        const float4* A = reinterpret_cast<const float4*>(oW2 + p * 64 + q * 16);
        const float4* B = reinterpret_cast<const float4*>(oW2 + (p + 16) * 64 + q * 16);
        float4 a, bq;
#define LW(kk, d0, d1, d2, d3) { a = A[kk]; bq = B[kk]; \
        d0 = f32x2{a.x, bq.x}; d1 = f32x2{a.y, bq.y}; \
        d2 = f32x2{a.z, bq.z}; d3 = f32x2{a.w, bq.w}; }
        LW(0, w2_0, w2_1, w2_2,  w2_3)
        LW(1, w2_4, w2_5, w2_6,  w2_7)
        LW(2, w2_8, w2_9, w2_10, w2_11)
        LW(3, w2_12, w2_13, w2_14, w2_15)
#undef LW
    }
    // S3: outputs {p, p+16}, k in [8q, 8q+8)
    f32x2 w3_0, w3_1, w3_2, w3_3, w3_4, w3_5, w3_6, w3_7;
    {
        const float4* A = reinterpret_cast<const float4*>(oW3 + p * 32 + q * 8);
        const float4* B = reinterpret_cast<const float4*>(oW3 + (p + 16) * 32 + q * 8);
        float4 a, bq;
#define LW(kk, d0, d1, d2, d3) { a = A[kk]; bq = B[kk]; \
        d0 = f32x2{a.x, bq.x}; d1 = f32x2{a.y, bq.y}; \
        d2 = f32x2{a.z, bq.z}; d3 = f32x2{a.w, bq.w}; }
        LW(0, w3_0, w3_1, w3_2, w3_3)
        LW(1, w3_4, w3_5, w3_6, w3_7)
#undef LW
    }
    const f32x2 b1pk = f32x2{ob1[r], ob1[r + 32]};
    const f32x2 b2pk = f32x2{ob2[p], ob2[p + 16]};
    const f32x2 b3pk = f32x2{ob3[p], ob3[p + 16]};

    const float brr = gbih[r]      + gbhh[r];
    const float bzz = gbih[32 + r] + gbhh[32 + r];
    const float bin = gbih[64 + r];
    const float bhn = gbhh[64 + r];

    const float* wrp  = &sWr[(hf * 24) * 32 + r];
    const float* wzp  = &sWz[(hf * 24) * 32 + r];
    const float* wnhp = &sWnh[(hf * 16) * 32 + r];
    const float* wnip = &sWni[r];

    const int hf4  = hf * 4;
    const int q4   = q * 4;
    const int q2   = q * 2;
    const int wsel = (q & 1) << 4;   // P->X write slot offset

    // ---- ODE MLP, P-layout in/out (pk {v[p], v[p+16]}), 20 b128 / call ----
    auto ode_f2 = [&](f32x2 y0, f32x2 y1, f32x2& o0, f32x2& o1) {
        bufw0[p + wsel] = (q & 1) ? y0.y : y0.x;   // stage y -> LDS[0..31]
        bufw1[p + wsel] = (q & 1) ? y1.y : y1.x;
        fence();
        f32x2 A0 = f32x2{0.f, 0.f}, A1 = f32x2{0.f, 0.f};
#define S1M(kk, wA, wB, wC, wD) { \
        float4 c0 = bb0[hf4 + kk], c1 = bb1[hf4 + kk]; \
        A0 = pkfma(wA, f32x2{c0.x, c0.x}, A0); A1 = pkfma(wA, f32x2{c1.x, c1.x}, A1); \
        A0 = pkfma(wB, f32x2{c0.y, c0.y}, A0); A1 = pkfma(wB, f32x2{c1.y, c1.y}, A1); \
        A0 = pkfma(wC, f32x2{c0.z, c0.z}, A0); A1 = pkfma(wC, f32x2{c1.z, c1.z}, A1); \
        A0 = pkfma(wD, f32x2{c0.w, c0.w}, A0); A1 = pkfma(wD, f32x2{c1.w, c1.w}, A1); }
        S1M(0, w1_0,  w1_1,  w1_2,  w1_3)
        S1M(1, w1_4,  w1_5,  w1_6,  w1_7)
        S1M(2, w1_8,  w1_9,  w1_10, w1_11)
        S1M(3, w1_12, w1_13, w1_14, w1_15)
#undef S1M
        // halves hold complementary k-ranges of pair {r, r+32}: ^32-sum
        f32x2 h10 = f32x2{fmaxf(xh32(A0.x) + b1pk.x, 0.f),
                          fmaxf(xh32(A0.y) + b1pk.y, 0.f)};
        f32x2 h11 = f32x2{fmaxf(xh32(A1.x) + b1pk.x, 0.f),
                          fmaxf(xh32(A1.y) + b1pk.y, 0.f)};
        bufw0[lane] = hf ? h10.y : h10.x;          // h1 -> LDS[0..63]
        bufw1[lane] = hf ? h11.y : h11.x;
        fence();
        f32x2 B0 = f32x2{0.f, 0.f}, B1 = f32x2{0.f, 0.f};
#define S2M(kk, wA, wB, wC, wD) { \
        float4 c0 = bb0[q4 + kk], c1 = bb1[q4 + kk]; \
        B0 = pkfma(wA, f32x2{c0.x, c0.x}, B0); B1 = pkfma(wA, f32x2{c1.x, c1.x}, B1); \
        B0 = pkfma(wB, f32x2{c0.y, c0.y}, B0); B1 = pkfma(wB, f32x2{c1.y, c1.y}, B1); \
        B0 = pkfma(wC, f32x2{c0.z, c0.z}, B0); B1 = pkfma(wC, f32x2{c1.z, c1.z}, B1); \
        B0 = pkfma(wD, f32x2{c0.w, c0.w}, B0); B1 = pkfma(wD, f32x2{c1.w, c1.w}, B1); }
        S2M(0, w2_0,  w2_1,  w2_2,  w2_3)
        S2M(1, w2_4,  w2_5,  w2_6,  w2_7)
        S2M(2, w2_8,  w2_9,  w2_10, w2_11)
        S2M(3, w2_12, w2_13, w2_14, w2_15)
#undef S2M
        // 4 quarters hold complementary k: ^16 then ^32 sum
        f32x2 h20 = f32x2{fmaxf(xh32(xh16(B0.x)) + b2pk.x, 0.f),
                          fmaxf(xh32(xh16(B0.y)) + b2pk.y, 0.f)};
        f32x2 h21 = f32x2{fmaxf(xh32(xh16(B1.x)) + b2pk.x, 0.f),
                          fmaxf(xh32(xh16(B1.y)) + b2pk.y, 0.f)};
        bufw0[p + wsel] = (q & 1) ? h20.y : h20.x;  // h2 -> LDS[0..31]
        bufw1[p + wsel] = (q & 1) ? h21.y : h21.x;
        fence();
        f32x2 C0 = f32x2{0.f, 0.f}, C1 = f32x2{0.f, 0.f};
#define S3M(kk, wA, wB, wC, wD) { \
        float4 c0 = bb0[q2 + kk], c1 = bb1[q2 + kk]; \
        C0 = pkfma(wA, f32x2{c0.x, c0.x}, C0); C1 = pkfma(wA, f32x2{c1.x, c1.x}, C1); \
        C0 = pkfma(wB, f32x2{c0.y, c0.y}, C0); C1 = pkfma(wB, f32x2{c1.y, c1.y}, C1); \
        C0 = pkfma(wC, f32x2{c0.z, c0.z}, C0); C1 = pkfma(wC, f32x2{c1.z, c1.z}, C1); \
        C0 = pkfma(wD, f32x2{c0.w, c0.w}, C0); C1 = pkfma(wD, f32x2{c1.w, c1.w}, C1); }
        S3M(0, w3_0, w3_1, w3_2, w3_3)
        S3M(1, w3_4, w3_5, w3_6, w3_7)
#undef S3M
        o0 = f32x2{xh32(xh16(C0.x)) + b3pk.x, xh32(xh16(C0.y)) + b3pk.y};
        o1 = f32x2{xh32(xh16(C1.x)) + b3pk.x, xh32(xh16(C1.y)) + b3pk.y};
    };

    // ---------- time loop ----------
    f32x2 hv0 = f32x2{0.f, 0.f}, hv1 = f32x2{0.f, 0.f};  // hidden, P layout
    float outv0 = 0.f, outv1 = 0.f;                      // GRU out, X layout

    #pragma unroll 1
    for (int s = 0; s < NS - 1; ++s) {
        const float* xrow0 = x + ((size_t)b0 * NS + s) * NI;
        const float* xrow1 = x + ((size_t)b1 * NS + s) * NI;
        // stage cat=[x(16); h(32)]: q0/q3 write x[p]; q1 h[p]; q2 h[p+16]
        float xv0 = xrow0[p];
        float xv1 = xrow1[p];
        int   sa  = p + ((q == 1) ? 16 : (q == 2) ? 32 : 0);
        float sv0 = (q == 1) ? hv0.x : (q == 2) ? hv0.y : xv0;
        float sv1 = (q == 1) ? hv1.x : (q == 2) ? hv1.y : xv1;
        bufw0[sa] = sv0;
        bufw1[sa] = sv1;
        fence();
        float hvX0 = bufw0[16 + r];   // prev hidden, X layout
        float hvX1 = bufw1[16 + r];

        float ar0 = 0.f, ar1 = 0.f, az0 = 0.f, az1 = 0.f;
        #pragma unroll
        for (int kk = 0; kk < 6; ++kk) {
            float4 c0 = bb0[hf * 6 + kk];
            float4 c1 = bb1[hf * 6 + kk];
            float w;
            w = wrp[(4*kk  )*32]; ar0 = fmaf(w, c0.x, ar0); ar1 = fmaf(w, c1.x, ar1);
            w = wrp[(4*kk+1)*32]; ar0 = fmaf(w, c0.y, ar0); ar1 = fmaf(w, c1.y, ar1);
            w = wrp[(4*kk+2)*32]; ar0 = fmaf(w, c0.z, ar0); ar1 = fmaf(w, c1.z, ar1);
            w = wrp[(4*kk+3)*32]; ar0 = fmaf(w, c0.w, ar0); ar1 = fmaf(w, c1.w, ar1);
            w = wzp[(4*kk  )*32]; az0 = fmaf(w, c0.x, az0); az1 = fmaf(w, c1.x, az1);
            w = wzp[(4*kk+1)*32]; az0 = fmaf(w, c0.y, az0); az1 = fmaf(w, c1.y, az1);
            w = wzp[(4*kk+2)*32]; az0 = fmaf(w, c0.z, az0); az1 = fmaf(w, c1.z, az1);
            w = wzp[(4*kk+3)*32]; az0 = fmaf(w, c0.w, az0); az1 = fmaf(w, c1.w, az1);
        }
        float in0 = 0.f, in1 = 0.f, hn0 = 0.f, hn1 = 0.f;
        #pragma unroll
        for (int kk = 0; kk < 4; ++kk) {
            float4 c0 = bb0[kk];
            float4 c1 = bb1[kk];
            float w;
            w = wnip[(4*kk  )*32]; in0 = fmaf(w, c0.x, in0); in1 = fmaf(w, c1.x, in1);
            w = wnip[(4*kk+1)*32]; in0 = fmaf(w, c0.y, in0); in1 = fmaf(w, c1.y, in1);
            w = wnip[(4*kk+2)*32]; in0 = fmaf(w, c0.z, in0); in1 = fmaf(w, c1.z, in1);
            w = wnip[(4*kk+3)*32]; in0 = fmaf(w, c0.w, in0); in1 = fmaf(w, c1.w, in1);
        }
        #pragma unroll
        for (int kk = 0; kk < 4; ++kk) {
            float4 c0 = bb0[4 + hf * 4 + kk];
            float4 c1 = bb1[4 + hf * 4 + kk];
            float w;
            w = wnhp[(4*kk  )*32]; hn0 = fmaf(w, c0.x, hn0); hn1 = fmaf(w, c1.x, hn1);
            w = wnhp[(4*kk+1)*32]; hn0 = fmaf(w, c0.y, hn0); hn1 = fmaf(w, c1.y, hn1);
            w = wnhp[(4*kk+2)*32]; hn0 = fmaf(w, c0.z, hn0); hn1 = fmaf(w, c1.z, hn1);
            w = wnhp[(4*kk+3)*32]; hn0 = fmaf(w, c0.w, hn0); hn1 = fmaf(w, c1.w, hn1);
        }
        ar0 = xh32(ar0) + brr;  ar1 = xh32(ar1) + brr;
        az0 = xh32(az0) + bzz;  az1 = xh32(az1) + bzz;
        hn0 = xh32(hn0) + bhn;  hn1 = xh32(hn1) + bhn;
        in0 += bin;             in1 += bin;

        float rg0 = 1.0f / (1.0f + __expf(-ar0));
        float rg1 = 1.0f / (1.0f + __expf(-ar1));
        float zg0 = 1.0f / (1.0f + __expf(-az0));
        float zg1 = 1.0f / (1.0f + __expf(-az1));
        float ng0 = tanhf(fmaf(rg0, hn0, in0));
        float ng1 = tanhf(fmaf(rg1, hn1, in1));
        outv0 = (1.0f - zg0) * ng0 + zg0 * hvX0;
        outv1 = (1.0f - zg1) * ng1 + zg1 * hvX1;

        if (s < NS - 2) {
            const float ddt0 = (t[(size_t)b0 * NS + s + 1] - t[(size_t)b0 * NS + s]) * 0.25f;
            const float ddt1 = (t[(size_t)b1 * NS + s + 1] - t[(size_t)b1 * NS + s]) * 0.25f;
            // X -> P conversion of outv
            bufw0[r] = outv0;     // dup writers (lane, lane^32), same value
            bufw1[r] = outv1;
            fence();
            f32x2 hi0 = f32x2{bufw0[p], bufw0[p + 16]};
            f32x2 hi1 = f32x2{bufw1[p], bufw1[p + 16]};
            #pragma unroll 1
            for (int sub = 0; sub < 4; ++sub) {
                f32x2 k1_0, k1_1, k2_0, k2_1, k3_0, k3_1,
                      k4_0, k4_1, k5_0, k5_1, k6_0, k6_1;
                ode_f2(hi0, hi1, k1_0, k1_1);
                ode_f2(pfm(ddt0, 0.2f * k1_0, hi0),
                       pfm(ddt1, 0.2f * k1_1, hi1), k2_0, k2_1);
                ode_f2(pfm(ddt0, pfm((float)(9.0/40.0), k2_0, (float)(3.0/40.0) * k1_0), hi0),
                       pfm(ddt1, pfm((float)(9.0/40.0), k2_1, (float)(3.0/40.0) * k1_1), hi1),
                       k3_0, k3_1);
                ode_f2(pfm(ddt0, pfm((float)(32.0/9.0), k3_0,
                                 pfm(-(float)(56.0/15.0), k2_0, (float)(44.0/45.0) * k1_0)), hi0),
                       pfm(ddt1, pfm((float)(32.0/9.0), k3_1,
                                 pfm(-(float)(56.0/15.0), k2_1, (float)(44.0/45.0) * k1_1)), hi1),
                       k4_0, k4_1);
                ode_f2(pfm(ddt0, pfm(-(float)(212.0/729.0), k4_0,
                                 pfm((float)(64448.0/6561.0), k3_0,
                                 pfm(-(float)(25360.0/2187.0), k2_0, (float)(19372.0/6561.0) * k1_0))), hi0),
                       pfm(ddt1, pfm(-(float)(212.0/729.0), k4_1,
                                 pfm((float)(64448.0/6561.0), k3_1,
                                 pfm(-(float)(25360.0/2187.0), k2_1, (float)(19372.0/6561.0) * k1_1))), hi1),
                       k5_0, k5_1);
                ode_f2(pfm(ddt0, pfm(-(float)(5103.0/18656.0), k5_0,
                                 pfm((float)(49.0/176.0), k4_0,
                                 pfm((float)(46732.0/5247.0), k3_0,
                                 pfm(-(float)(355.0/33.0), k2_0, (float)(9017.0/3168.0) * k1_0)))), hi0),
                       pfm(ddt1, pfm(-(float)(5103.0/18656.0), k5_1,
                                 pfm((float)(49.0/176.0), k4_1,
                                 pfm((float)(46732.0/5247.0), k3_1,
                                 pfm(-(float)(355.0/33.0), k2_1, (float)(9017.0/3168.0) * k1_1)))), hi1),
                       k6_0, k6_1);
                hi0 = pfm(ddt0, pfm((float)(11.0/84.0), k6_0,
                                pfm(-(float)(2187.0/6784.0), k5_0,
                                pfm((float)(125.0/192.0), k4_0,
                                pfm((float)(500.0/1113.0), k3_0, (float)(35.0/384.0) * k1_0)))), hi0);
                hi1 = pfm(ddt1, pfm((float)(11.0/84.0), k6_1,
                                pfm(-(float)(2187.0/6784.0), k5_1,
                                pfm((float)(125.0/192.0), k4_1,
                                pfm((float)(500.0/1113.0), k3_1, (float)(35.0/384.0) * k1_1)))), hi1);
            }
            hv0 = hi0;
            hv1 = hi1;
        }
    }

    // ---------- FC head: relu(out @ fW1.T + fb1) @ fW2.T + fb2 ----------
    bufw0[hf * 32 + r] = outv0;
    bufw1[hf * 32 + r] = outv1;
    fence();
    f32x2 acc0  = f32x2{fb1[lane], 0.0f};
    f32x2 acc1h = f32x2{fb1[lane], 0.0f};
    {
        const float4* fw = reinterpret_cast<const float4*>(fW1) + lane * 8;
        #pragma unroll
        for (int kk = 0; kk < 8; ++kk) {
            float4 wv = fw[kk];
            float4 c0 = bb0[kk];
            float4 c1 = bb1[kk];
            acc0  = pkfma(f32x2{wv.x, wv.y}, f32x2{c0.x, c0.y}, acc0);
            acc0  = pkfma(f32x2{wv.z, wv.w}, f32x2{c0.z, c0.w}, acc0);
            acc1h = pkfma(f32x2{wv.x, wv.y}, f32x2{c1.x, c1.y}, acc1h);
            acc1h = pkfma(f32x2{wv.z, wv.w}, f32x2{c1.z, c1.w}, acc1h);
        }
    }
    float fw2v = fW2[lane];
    float pa = fmaxf(acc0.x + acc0.y, 0.0f) * fw2v;
    float pb = fmaxf(acc1h.x + acc1h.y, 0.0f) * fw2v;
    #pragma unroll
    for (int m = 1; m < 64; m <<= 1) {
        pa += __shfl_xor(pa, m, 64);
        pb += __shfl_xor(pb, m, 64);
    }
    if (lane == 0) {
        float bias = fb2[0];
        outp[b0] = pa + bias;
        outp[b1] = pb + bias;
    }
}

extern "C" void kernel_launch(void* const* d_in, const int* in_sizes, int n_in,
                              void* d_out, int out_size, void* d_ws, size_t ws_size,
                              hipStream_t stream) {
    (void)in_sizes; (void)n_in; (void)d_ws; (void)ws_size; (void)out_size;
    odernn_kernel<<<dim3(NB / 8), dim3(256), 0, stream>>>(
        (const float*)d_in[0],  (const float*)d_in[1],
        (const float*)d_in[2],  (const float*)d_in[3],
        (const float*)d_in[4],  (const float*)d_in[5],
        (const float*)d_in[6],  (const float*)d_in[7],
        (const float*)d_in[8],  (const float*)d_in[9],
        (const float*)d_in[10], (const float*)d_in[11],
        (const float*)d_in[12], (const float*)d_in[13],
        (const float*)d_in[14], (const float*)d_in[15],
        (float*)d_out);
}